// Round 5
// baseline (818.703 us; speedup 1.0000x reference)
//
#include <hip/hip_runtime.h>

// Problem constants
#define BB 4
#define CC 16
#define HH 256
#define WW 256
#define NN (HH*WW)      // 65536
#define SS 100
#define NCHK 16         // n-chunks per (b,q), 4096 n each
#define EPSV 1e-32f

// ws layout (float offsets)
#define PPART_OFF 0u                    // [8][16 chunk][17 c][100 s] = 217600
#define PQ_OFF    217600u               // [8][17][100]               = 13600
#define SPFN_OFF  231200u               // [8][16][100]               = 12800
#define PFSP_OFF  244000u               // [4][16][65536]             = 4194304
// total 4438304 floats = 17.8 MB

__device__ __forceinline__ float dot4(const float4& a, const float4& b) {
    return a.x * b.x + a.y * b.y + a.z * b.z + a.w * b.w;
}
__device__ __forceinline__ float sum4(const float4& a) {
    return a.x + a.y + a.z + a.w;
}
__device__ __forceinline__ void fma2g(float2& a, float c1, const float2& v1,
                                      float c2, const float2& v2) {
    a.x += c1 * v1.x + c2 * v2.x;
    a.y += c1 * v1.y + c2 * v2.y;
}

// ---------------- pass1 macros (named regs, no arrays) ----------------
#define ACC_LIST(F) \
    F(0,0) F(0,1) F(0,2) F(0,3) F(0,4) \
    F(1,0) F(1,1) F(1,2) F(1,3) F(1,4) \
    F(2,0) F(2,1) F(2,2) F(2,3) F(2,4) \
    F(3,0) F(3,1) F(3,2) F(3,3) F(3,4)
#define DECL_ACC(c, s) float a##c##s = 0.f;
#define RED1(x) x += __shfl_xor(x, 1); x += __shfl_xor(x, 2); \
    x += __shfl_xor(x, 4); x += __shfl_xor(x, 8); \
    x += __shfl_xor(x, 16); x += __shfl_xor(x, 32);
#define RED_ACC(c, s) RED1(a##c##s)
#define ST_ACC(c, s) ws[pbase + (size_t)(cbase + c) * SS + sbase + s] = a##c##s;

#define QLOAD(S, off) \
    S##0 = *(const float4*)(qp0 + (off)); \
    S##1 = *(const float4*)(qp1 + (off)); \
    S##2 = *(const float4*)(qp2 + (off)); \
    S##3 = *(const float4*)(qp3 + (off)); \
    S##4 = *(const float4*)(qp4 + (off));

// pf from LDS: 4 ds_read_b128 at compile-time offsets; 20 dot4 + qsum
#define PFDOT(S, st) { \
    const float4* pfp = (const float4*)&pfl[(cbase << 9) + (st) * 256 + (lane << 2)]; \
    float4 p0 = pfp[0], p1 = pfp[128], p2 = pfp[256], p3 = pfp[384]; \
    a00 += dot4(p0, S##0); a01 += dot4(p0, S##1); a02 += dot4(p0, S##2); a03 += dot4(p0, S##3); a04 += dot4(p0, S##4); \
    a10 += dot4(p1, S##0); a11 += dot4(p1, S##1); a12 += dot4(p1, S##2); a13 += dot4(p1, S##3); a14 += dot4(p1, S##4); \
    a20 += dot4(p2, S##0); a21 += dot4(p2, S##1); a22 += dot4(p2, S##2); a23 += dot4(p2, S##3); a24 += dot4(p2, S##4); \
    a30 += dot4(p3, S##0); a31 += dot4(p3, S##1); a32 += dot4(p3, S##2); a33 += dot4(p3, S##3); a34 += dot4(p3, S##4); \
    qs0 += sum4(S##0); qs1 += sum4(S##1); qs2 += sum4(S##2); qs3 += sum4(S##3); qs4 += sum4(S##4); }

// stage pf window [16][512] floats: 2048 float4 slots by 256 threads
#define STAGE(win) { \
    _Pragma("unroll") \
    for (int it = 0; it < 8; ++it) { \
        int sl = it * 256 + tid; \
        int cst = sl >> 7, pos = sl & 127; \
        ((float4*)pfl)[sl] = *(const float4*)(PF + (size_t)cst * NN + n0 + (win) * 512 + pos * 4); \
    } }

// K1: partial P[c,s] = sum_n pf[c,n]*Q[s,n], qsum[s] = sum_n Q[s,n]
// Only 5 global Q streams per BLOCK (shared by 4 waves); pf via LDS window.
// Grid (chunk, stile, bq): lin%8 == chunk%8 -> all stiles+bq of a chunk on one
// XCD, so pf re-reads hit that XCD's L2 (2 MB working set per XCD).
__global__ __launch_bounds__(256, 4) void k_pass1(const float* __restrict__ pf,
                                                  const float* __restrict__ Q1,
                                                  const float* __restrict__ Q2,
                                                  float* __restrict__ ws) {
    int chunk = blockIdx.x;   // 0..15
    int stile = blockIdx.y;   // 0..19
    int bq    = blockIdx.z;   // 0..7
    int b = bq >> 1, q = bq & 1;
    const float* Q  = (q ? Q2 : Q1) + (size_t)b * SS * NN;
    const float* PF = pf + (size_t)b * CC * NN;
    int tid = threadIdx.x, w = tid >> 6, lane = tid & 63;
    int cbase = w * 4, sbase = stile * 5;
    int n0 = chunk * 4096;

    __shared__ float pfl[CC * 512];   // 32 KB window

    const float* qp0 = Q + (size_t)(sbase + 0) * NN + n0 + (lane << 2);
    const float* qp1 = Q + (size_t)(sbase + 1) * NN + n0 + (lane << 2);
    const float* qp2 = Q + (size_t)(sbase + 2) * NN + n0 + (lane << 2);
    const float* qp3 = Q + (size_t)(sbase + 3) * NN + n0 + (lane << 2);
    const float* qp4 = Q + (size_t)(sbase + 4) * NN + n0 + (lane << 2);

    ACC_LIST(DECL_ACC)
    float qs0 = 0.f, qs1 = 0.f, qs2 = 0.f, qs3 = 0.f, qs4 = 0.f;
    float4 A0, A1, A2, A3, A4, B0, B1, B2, B3, B4;

    STAGE(0)
    __syncthreads();
    QLOAD(A, 0)
    #pragma unroll
    for (int win = 0; win < 8; ++win) {
        QLOAD(B, (win * 512 + 256) & 4095)
        PFDOT(A, 0)
        QLOAD(A, (win * 512 + 512) & 4095)   // wraps to 0 on last (unused)
        PFDOT(B, 1)
        if (win < 7) {
            __syncthreads();
            STAGE(win + 1)
            __syncthreads();
        }
    }

    ACC_LIST(RED_ACC)
    RED1(qs0) RED1(qs1) RED1(qs2) RED1(qs3) RED1(qs4)

    if (lane == 0) {
        size_t pbase = PPART_OFF + (size_t)(bq * NCHK + chunk) * 17 * SS;
        ACC_LIST(ST_ACC)
        if (w == 0) {
            ws[pbase + 16 * SS + sbase + 0] = qs0;
            ws[pbase + 16 * SS + sbase + 1] = qs1;
            ws[pbase + 16 * SS + sbase + 2] = qs2;
            ws[pbase + 16 * SS + sbase + 3] = qs3;
            ws[pbase + 16 * SS + sbase + 4] = qs4;
        }
    }
}

// K2: reduce PPART over 16 chunks -> PQ[bq][17][100]
__global__ __launch_bounds__(128) void k_reduceP(float* __restrict__ ws) {
    int c  = blockIdx.x;   // 0..16
    int bq = blockIdx.y;   // 0..7
    int s  = threadIdx.x;
    if (s < SS) {
        float a = 0.f;
        #pragma unroll
        for (int ch = 0; ch < NCHK; ++ch)
            a += ws[PPART_OFF + ((size_t)(bq * NCHK + ch) * 17 + c) * SS + s];
        ws[PQ_OFF + ((size_t)bq * 17 + c) * SS + s] = a;
    }
}

// K3: rels (in LDS) + spf_n[c,s] = (sum_t rels[s,t]P[c,t]) / (sum_t rels[s,t]qsum[t]+eps)
__global__ __launch_bounds__(256) void k_finalize(const float* __restrict__ spf1,
                                                  const float* __restrict__ spf2,
                                                  float* __restrict__ ws) {
    int bq = blockIdx.x;  // 0..7
    int b = bq >> 1, q = bq & 1;
    __shared__ float sp[CC][SS];
    __shared__ float rl[SS][SS + 1];
    __shared__ float Pl[CC * SS];
    __shared__ float qs[SS];
    __shared__ float den[SS];
    int tid = threadIdx.x;

    const float* spf = (q ? spf2 : spf1) + (size_t)b * CC * SS;
    for (int i = tid; i < CC * SS; i += 256) sp[i / SS][i % SS] = spf[i];
    __syncthreads();
    for (int i = tid; i < SS * SS; i += 256) {
        int s = i / SS, t = i % SS;
        float d2 = 0.f;
        #pragma unroll
        for (int c = 0; c < CC; ++c) {
            float d = sp[c][t] - sp[c][s];
            d2 += d * d;
        }
        rl[s][t] = expf(-d2);
    }
    const float* pq = ws + PQ_OFF + (size_t)bq * 17 * SS;
    for (int idx = tid; idx < CC * SS; idx += 256) Pl[idx] = pq[idx];
    if (tid < SS) qs[tid] = pq[16 * SS + tid];
    __syncthreads();
    if (tid < SS) {
        float a = 0.f;
        for (int t = 0; t < SS; ++t) a += rl[tid][t] * qs[t];
        den[tid] = a + EPSV;
    }
    __syncthreads();
    float* sout = ws + SPFN_OFF + (size_t)bq * CC * SS;
    for (int idx = tid; idx < CC * SS; idx += 256) {
        int c = idx / SS, s = idx % SS;
        float a = 0.f;
        for (int t = 0; t < SS; ++t) a += rl[s][t] * Pl[c * SS + t];
        sout[idx] = a / den[s];
    }
}

// K4: pf_sp[c,n] = sum_s spf1n[c,s]Q1[s,n] + spf2n[c,s]Q2[s,n]
// 2 px/thread (float2), 2048 waves chip-wide, 2-deep explicit prefetch.
#define P2FMA(X, s) { \
    _Pragma("unroll") for (int g = 0; g < 4; ++g) { \
        float4 s1 = *(const float4*)&sp[0][s][g * 4]; \
        float4 s2 = *(const float4*)&sp[1][s][g * 4]; \
        fma2g(acc[g*4+0], s1.x, X##1, s2.x, X##2); \
        fma2g(acc[g*4+1], s1.y, X##1, s2.y, X##2); \
        fma2g(acc[g*4+2], s1.z, X##1, s2.z, X##2); \
        fma2g(acc[g*4+3], s1.w, X##1, s2.w, X##2); } }

__global__ __launch_bounds__(128) void k_pass2(const float* __restrict__ Q1,
                                               const float* __restrict__ Q2,
                                               float* __restrict__ ws) {
    int blk = blockIdx.x;   // 0..255
    int b   = blockIdx.y;
    __shared__ float sp[2][SS][CC];
    int tid = threadIdx.x;
    const float* spin = ws + SPFN_OFF + (size_t)b * 2 * CC * SS;
    for (int idx = tid; idx < 2 * CC * SS; idx += 128) {
        int qq = idx / (CC * SS), rem = idx % (CC * SS);
        int c = rem / SS, s = rem % SS;
        sp[qq][s][c] = spin[idx];
    }
    __syncthreads();
    int n = blk * 256 + tid * 2;
    const float* q1p = Q1 + (size_t)b * SS * NN + n;
    const float* q2p = Q2 + (size_t)b * SS * NN + n;
    float2 acc[CC];
    #pragma unroll
    for (int c = 0; c < CC; ++c) acc[c] = make_float2(0.f, 0.f);
    float2 A1, A2, B1, B2;
    A1 = *(const float2*)(q1p);
    A2 = *(const float2*)(q2p);
    #pragma unroll 2
    for (int s = 0; s < 98; s += 2) {
        B1 = *(const float2*)(q1p + (size_t)(s + 1) * NN);
        B2 = *(const float2*)(q2p + (size_t)(s + 1) * NN);
        P2FMA(A, s)
        A1 = *(const float2*)(q1p + (size_t)(s + 2) * NN);
        A2 = *(const float2*)(q2p + (size_t)(s + 2) * NN);
        P2FMA(B, s + 1)
    }
    B1 = *(const float2*)(q1p + (size_t)99 * NN);
    B2 = *(const float2*)(q2p + (size_t)99 * NN);
    P2FMA(A, 98)
    P2FMA(B, 99)
    float* o = ws + PFSP_OFF + (size_t)b * CC * NN + n;
    #pragma unroll
    for (int c = 0; c < CC; ++c)
        *(float2*)(o + (size_t)c * NN) = acc[c];
}

// K5: 3x3 conv (cross-correlation, SAME zero padding), 16 -> 2 channels, + bias
__global__ __launch_bounds__(256) void k_conv(const float* __restrict__ w_ds,
                                              const float* __restrict__ b_ds,
                                              const float* __restrict__ ws,
                                              float* __restrict__ out) {
    int b = blockIdx.y;
    int n = blockIdx.x * 256 + threadIdx.x;
    __shared__ float wl[2][CC][9];
    __shared__ float bl[2];
    for (int i = threadIdx.x; i < 2 * CC * 9; i += 256)
        ((float*)wl)[i] = w_ds[i];
    if (threadIdx.x < 2) bl[threadIdx.x] = b_ds[threadIdx.x];
    __syncthreads();
    int y = n >> 8, x = n & 255;
    const float* base = ws + PFSP_OFF + (size_t)b * CC * NN;
    float a0 = bl[0], a1 = bl[1];
    for (int c = 0; c < CC; ++c) {
        const float* pc = base + (size_t)c * NN;
        #pragma unroll
        for (int dy = -1; dy <= 1; ++dy) {
            int yy = y + dy;
            if (yy < 0 || yy >= HH) continue;
            #pragma unroll
            for (int dx = -1; dx <= 1; ++dx) {
                int xx = x + dx;
                if (xx < 0 || xx >= WW) continue;
                float v = pc[(size_t)yy * WW + xx];
                int k = (dy + 1) * 3 + (dx + 1);
                a0 += v * wl[0][c][k];
                a1 += v * wl[1][c][k];
            }
        }
    }
    out[((size_t)b * 2 + 0) * NN + n] = a0;
    out[((size_t)b * 2 + 1) * NN + n] = a1;
}

extern "C" void kernel_launch(void* const* d_in, const int* in_sizes, int n_in,
                              void* d_out, int out_size, void* d_ws, size_t ws_size,
                              hipStream_t stream) {
    const float* pf   = (const float*)d_in[0];
    const float* spf1 = (const float*)d_in[1];
    const float* spf2 = (const float*)d_in[2];
    const float* Q1   = (const float*)d_in[3];
    const float* Q2   = (const float*)d_in[4];
    const float* w_ds = (const float*)d_in[5];
    const float* b_ds = (const float*)d_in[6];
    float* ws  = (float*)d_ws;
    float* out = (float*)d_out;

    k_pass1<<<dim3(NCHK, 20, 8), 256, 0, stream>>>(pf, Q1, Q2, ws);
    k_reduceP<<<dim3(17, 8), 128, 0, stream>>>(ws);
    k_finalize<<<8, 256, 0, stream>>>(spf1, spf2, ws);
    k_pass2<<<dim3(NN / 256, BB), 128, 0, stream>>>(Q1, Q2, ws);
    k_conv<<<dim3(NN / 256, BB), 256, 0, stream>>>(w_ds, b_ds, ws, out);
}

// Round 6
// 244.140 us; speedup vs baseline: 3.3534x; 3.3534x over previous
//
#include <hip/hip_runtime.h>

// Problem constants
#define BB 4
#define CC 16
#define HH 256
#define WW 256
#define NN (HH*WW)      // 65536
#define SS 100
#define NCHK 64         // n-chunks per (b,q), 1024 n each
#define EPSV 1e-32f

// ws layout (float offsets)
#define PPART_OFF 0u                    // [8 bq][64 chunk][100 s][17] = 870400
#define PQ_OFF    870400u               // [8][17][100]                = 13600
#define SPFN_OFF  884000u               // [8][16][100]                = 12800
#define PFSP_OFF  896800u               // [4][16][65536]              = 4194304
// total 5,091,104 floats = 20.4 MB

__device__ __forceinline__ float dot4(const float4& a, const float4& b) {
    return a.x * b.x + a.y * b.y + a.z * b.z + a.w * b.w;
}
__device__ __forceinline__ float sum4(const float4& a) {
    return a.x + a.y + a.z + a.w;
}
__device__ __forceinline__ void fma4(float4& a, float s, const float4& v) {
    a.x += s * v.x; a.y += s * v.y; a.z += s * v.z; a.w += s * v.w;
}

#define RED1(x) x += __shfl_xor(x, 1); x += __shfl_xor(x, 2); \
    x += __shfl_xor(x, 4); x += __shfl_xor(x, 8); \
    x += __shfl_xor(x, 16); x += __shfl_xor(x, 32);

// ---- pass1 macros: Q double-buffer load + per-s compute/reduce/store ----
#define QLD(X, sidx) \
    X##0 = *(const float4*)(qb + (size_t)(sidx) * NN); \
    X##1 = *(const float4*)(qb + (size_t)(sidx) * NN + 256); \
    X##2 = *(const float4*)(qb + (size_t)(sidx) * NN + 512); \
    X##3 = *(const float4*)(qb + (size_t)(sidx) * NN + 768);

#define COMP(X, sidx) { \
    float t0 = dot4(p00, X##0) + dot4(p01, X##1) + dot4(p02, X##2) + dot4(p03, X##3); \
    float t1 = dot4(p10, X##0) + dot4(p11, X##1) + dot4(p12, X##2) + dot4(p13, X##3); \
    float t2 = dot4(p20, X##0) + dot4(p21, X##1) + dot4(p22, X##2) + dot4(p23, X##3); \
    float t3 = dot4(p30, X##0) + dot4(p31, X##1) + dot4(p32, X##2) + dot4(p33, X##3); \
    RED1(t0) RED1(t1) RED1(t2) RED1(t3) \
    if (w == 0) { \
        float qv = sum4(X##0) + sum4(X##1) + sum4(X##2) + sum4(X##3); \
        RED1(qv) \
        if (lane == 0) pout[(size_t)(sidx) * 17 + 16] = qv; \
    } \
    if (lane == 0) { \
        float* o = pout + (size_t)(sidx) * 17 + cbase; \
        o[0] = t0; o[1] = t1; o[2] = t2; o[3] = t3; \
    } }

// K1: partial P[c,s] = sum_n pf[c,n]*Q[s,n], qsum[s] = sum_n Q[s,n]
// pass2-shaped: pf in REGISTERS (16 float4/lane, loaded once), ONE walking
// Q stream per lane (4x1KB coalesced loads per s, double-buffered), no LDS,
// no barriers. Wave owns a c-quad; 4 waves share Q bytes via L1.
// Grid: x = chunk (64), y = bq (8). 512 long-lived blocks.
__global__ __launch_bounds__(256) void k_pass1(const float* __restrict__ pf,
                                               const float* __restrict__ Q1,
                                               const float* __restrict__ Q2,
                                               float* __restrict__ ws) {
    int chunk = blockIdx.x;   // 0..63
    int bq    = blockIdx.y;   // 0..7
    int b = bq >> 1, q = bq & 1;
    const float* Q  = (q ? Q2 : Q1) + (size_t)b * SS * NN;
    const float* PF = pf + (size_t)b * CC * NN;
    int tid = threadIdx.x, w = tid >> 6, lane = tid & 63;
    int cbase = w * 4;
    int n0 = chunk * 1024;

    const float* qb  = Q + n0 + lane * 4;
    const float* pb0 = PF + (size_t)(cbase + 0) * NN + n0 + lane * 4;
    const float* pb1 = PF + (size_t)(cbase + 1) * NN + n0 + lane * 4;
    const float* pb2 = PF + (size_t)(cbase + 2) * NN + n0 + lane * 4;
    const float* pb3 = PF + (size_t)(cbase + 3) * NN + n0 + lane * 4;

    // pf tile: 16 float4 per lane, persistent in registers
    float4 p00 = *(const float4*)(pb0 +   0), p01 = *(const float4*)(pb0 + 256),
           p02 = *(const float4*)(pb0 + 512), p03 = *(const float4*)(pb0 + 768);
    float4 p10 = *(const float4*)(pb1 +   0), p11 = *(const float4*)(pb1 + 256),
           p12 = *(const float4*)(pb1 + 512), p13 = *(const float4*)(pb1 + 768);
    float4 p20 = *(const float4*)(pb2 +   0), p21 = *(const float4*)(pb2 + 256),
           p22 = *(const float4*)(pb2 + 512), p23 = *(const float4*)(pb2 + 768);
    float4 p30 = *(const float4*)(pb3 +   0), p31 = *(const float4*)(pb3 + 256),
           p32 = *(const float4*)(pb3 + 512), p33 = *(const float4*)(pb3 + 768);

    float* pout = ws + PPART_OFF + (size_t)(bq * NCHK + chunk) * SS * 17;

    float4 A0, A1, A2, A3, B0, B1, B2, B3;
    QLD(A, 0)
    for (int s = 0; s < 98; s += 2) {
        QLD(B, s + 1)
        COMP(A, s)
        QLD(A, s + 2)
        COMP(B, s + 1)
    }
    QLD(B, 99)
    COMP(A, 98)
    COMP(B, 99)
}

// K2: PQ[bq][c][s] = sum_{chunk} PPART[bq][chunk][s][c]   (c: 0..16, 16=qsum)
__global__ __launch_bounds__(256) void k_reduceP(float* __restrict__ ws) {
    int bq = blockIdx.x;  // 0..7
    int tid = threadIdx.x;
    const float* pp = ws + PPART_OFF + (size_t)bq * NCHK * SS * 17;
    for (int idx = tid; idx < 17 * SS; idx += 256) {
        int c = idx / SS, s = idx % SS;
        float a = 0.f;
        #pragma unroll 4
        for (int ch = 0; ch < NCHK; ++ch)
            a += pp[(size_t)ch * SS * 17 + (size_t)s * 17 + c];
        ws[PQ_OFF + (size_t)bq * 17 * SS + idx] = a;
    }
}

// K3: rels (in LDS) + spf_n[c,s] = (sum_t rels[s,t]P[c,t]) / (sum_t rels[s,t]qsum[t]+eps)
__global__ __launch_bounds__(256) void k_finalize(const float* __restrict__ spf1,
                                                  const float* __restrict__ spf2,
                                                  float* __restrict__ ws) {
    int bq = blockIdx.x;  // 0..7
    int b = bq >> 1, q = bq & 1;
    __shared__ float sp[CC][SS];
    __shared__ float rl[SS][SS + 1];
    __shared__ float Pl[CC * SS];
    __shared__ float qs[SS];
    __shared__ float den[SS];
    int tid = threadIdx.x;

    const float* spf = (q ? spf2 : spf1) + (size_t)b * CC * SS;
    for (int i = tid; i < CC * SS; i += 256) sp[i / SS][i % SS] = spf[i];
    __syncthreads();
    for (int i = tid; i < SS * SS; i += 256) {
        int s = i / SS, t = i % SS;
        float d2 = 0.f;
        #pragma unroll
        for (int c = 0; c < CC; ++c) {
            float d = sp[c][t] - sp[c][s];
            d2 += d * d;
        }
        rl[s][t] = expf(-d2);
    }
    const float* pq = ws + PQ_OFF + (size_t)bq * 17 * SS;
    for (int idx = tid; idx < CC * SS; idx += 256) Pl[idx] = pq[idx];
    if (tid < SS) qs[tid] = pq[16 * SS + tid];
    __syncthreads();
    if (tid < SS) {
        float a = 0.f;
        for (int t = 0; t < SS; ++t) a += rl[tid][t] * qs[t];
        den[tid] = a + EPSV;
    }
    __syncthreads();
    float* sout = ws + SPFN_OFF + (size_t)bq * CC * SS;
    for (int idx = tid; idx < CC * SS; idx += 256) {
        int c = idx / SS, s = idx % SS;
        float a = 0.f;
        for (int t = 0; t < SS; ++t) a += rl[s][t] * Pl[c * SS + t];
        sout[idx] = a / den[s];
    }
}

// K4: pf_sp[c,n] = sum_s spf1n[c,s]Q1[s,n] + spf2n[c,s]Q2[s,n]
// Known-good R2 version: 4 px/thread float4, spf_n transposed in LDS.
__global__ __launch_bounds__(256) void k_pass2(const float* __restrict__ Q1,
                                               const float* __restrict__ Q2,
                                               float* __restrict__ ws) {
    int blk = blockIdx.x;   // 0..N/1024-1
    int b   = blockIdx.y;
    __shared__ float sp[2][SS][CC];
    int tid = threadIdx.x;
    const float* spin = ws + SPFN_OFF + (size_t)b * 2 * CC * SS;
    for (int idx = tid; idx < 2 * CC * SS; idx += 256) {
        int qq  = idx / (CC * SS);
        int rem = idx % (CC * SS);
        int c = rem / SS, s = rem % SS;
        sp[qq][s][c] = spin[idx];
    }
    __syncthreads();
    int n = blk * 1024 + tid * 4;
    const float* q1p = Q1 + (size_t)b * SS * NN + n;
    const float* q2p = Q2 + (size_t)b * SS * NN + n;
    float4 acc[CC];
    #pragma unroll
    for (int c = 0; c < CC; ++c) acc[c] = make_float4(0.f, 0.f, 0.f, 0.f);
    #pragma unroll 2
    for (int s = 0; s < SS; ++s) {
        float4 v1 = *(const float4*)(q1p + (size_t)s * NN);
        float4 v2 = *(const float4*)(q2p + (size_t)s * NN);
        #pragma unroll
        for (int g = 0; g < 4; ++g) {
            float4 s1v = *(const float4*)&sp[0][s][g * 4];
            float4 s2v = *(const float4*)&sp[1][s][g * 4];
            fma4(acc[g * 4 + 0], s1v.x, v1); fma4(acc[g * 4 + 0], s2v.x, v2);
            fma4(acc[g * 4 + 1], s1v.y, v1); fma4(acc[g * 4 + 1], s2v.y, v2);
            fma4(acc[g * 4 + 2], s1v.z, v1); fma4(acc[g * 4 + 2], s2v.z, v2);
            fma4(acc[g * 4 + 3], s1v.w, v1); fma4(acc[g * 4 + 3], s2v.w, v2);
        }
    }
    float* o = ws + PFSP_OFF + (size_t)b * CC * NN + n;
    #pragma unroll
    for (int c = 0; c < CC; ++c)
        *(float4*)(o + (size_t)c * NN) = acc[c];
}

// K5: 3x3 conv (cross-correlation, SAME zero padding), 16 -> 2 channels, + bias
__global__ __launch_bounds__(256) void k_conv(const float* __restrict__ w_ds,
                                              const float* __restrict__ b_ds,
                                              const float* __restrict__ ws,
                                              float* __restrict__ out) {
    int b = blockIdx.y;
    int n = blockIdx.x * 256 + threadIdx.x;
    __shared__ float wl[2][CC][9];
    __shared__ float bl[2];
    for (int i = threadIdx.x; i < 2 * CC * 9; i += 256)
        ((float*)wl)[i] = w_ds[i];
    if (threadIdx.x < 2) bl[threadIdx.x] = b_ds[threadIdx.x];
    __syncthreads();
    int y = n >> 8, x = n & 255;
    const float* base = ws + PFSP_OFF + (size_t)b * CC * NN;
    float a0 = bl[0], a1 = bl[1];
    for (int c = 0; c < CC; ++c) {
        const float* pc = base + (size_t)c * NN;
        #pragma unroll
        for (int dy = -1; dy <= 1; ++dy) {
            int yy = y + dy;
            if (yy < 0 || yy >= HH) continue;
            #pragma unroll
            for (int dx = -1; dx <= 1; ++dx) {
                int xx = x + dx;
                if (xx < 0 || xx >= WW) continue;
                float v = pc[(size_t)yy * WW + xx];
                int k = (dy + 1) * 3 + (dx + 1);
                a0 += v * wl[0][c][k];
                a1 += v * wl[1][c][k];
            }
        }
    }
    out[((size_t)b * 2 + 0) * NN + n] = a0;
    out[((size_t)b * 2 + 1) * NN + n] = a1;
}

extern "C" void kernel_launch(void* const* d_in, const int* in_sizes, int n_in,
                              void* d_out, int out_size, void* d_ws, size_t ws_size,
                              hipStream_t stream) {
    const float* pf   = (const float*)d_in[0];
    const float* spf1 = (const float*)d_in[1];
    const float* spf2 = (const float*)d_in[2];
    const float* Q1   = (const float*)d_in[3];
    const float* Q2   = (const float*)d_in[4];
    const float* w_ds = (const float*)d_in[5];
    const float* b_ds = (const float*)d_in[6];
    float* ws  = (float*)d_ws;
    float* out = (float*)d_out;

    k_pass1<<<dim3(NCHK, 8), 256, 0, stream>>>(pf, Q1, Q2, ws);
    k_reduceP<<<8, 256, 0, stream>>>(ws);
    k_finalize<<<8, 256, 0, stream>>>(spf1, spf2, ws);
    k_pass2<<<dim3(NN / 1024, BB), 256, 0, stream>>>(Q1, Q2, ws);
    k_conv<<<dim3(NN / 256, BB), 256, 0, stream>>>(w_ds, b_ds, ws, out);
}

// Round 8
// 208.814 us; speedup vs baseline: 3.9207x; 1.1692x over previous
//
#include <hip/hip_runtime.h>

// Problem constants
#define BB 4
#define CC 16
#define HH 256
#define WW 256
#define NN (HH*WW)      // 65536
#define SS 100
#define EPSV 1e-32f

// ws layout (float offsets)
#define PQ_OFF    0u                      // [8 bq][16 wgrp][1700]    = 217600
#define SPFN_OFF  217600u                 // [8 bq][16 c][100 s]      = 12800
#define PFSP_OFF  230400u                 // [4][16][65536]           = 4194304
#define PPART_OFF PFSP_OFF                // [8 bq][256 win][100 s][17] = 3481600
// PPART aliases PFSP: consumed by k_reduceP/k_finalize before k_pass2 overwrites.
// total = 230400 + 4194304 floats = 17.7 MB

__device__ __forceinline__ float dot4(const float4& a, const float4& b) {
    return a.x * b.x + a.y * b.y + a.z * b.z + a.w * b.w;
}
__device__ __forceinline__ void fma2g(float2& a, float c1, const float2& v1,
                                      float c2, const float2& v2) {
    a.x += c1 * v1.x + c2 * v2.x;
    a.y += c1 * v1.y + c2 * v2.y;
}

// Full 64-lane sum via DPP (VALU pipe, NOT the DS pipe). Result in lane 63.
__device__ __forceinline__ float dpp_sum64(float x) {
    #define DPPADD(ctrl) \
        x += __int_as_float(__builtin_amdgcn_update_dpp( \
            0, __float_as_int(x), ctrl, 0xF, 0xF, true));
    DPPADD(0x111)  // row_shr:1
    DPPADD(0x112)  // row_shr:2
    DPPADD(0x114)  // row_shr:4
    DPPADD(0x118)  // row_shr:8  -> lane15 of each row16 holds row sum
    DPPADD(0x142)  // row_bcast:15
    DPPADD(0x143)  // row_bcast:31 -> lane63 = all 64
    #undef DPPADD
    return x;
}

// ---------------- pass1 (K1) ----------------
// Wave owns a 256-px window + ALL 16 c (pf in 16 float4 regs). Per s: ONE
// 1KB coalesced Q load, 16 dot4, 17 DPP reductions, lane-63 stores 17 floats.
// 4-deep named prefetch. No LDS, no barriers, no DS-pipe ops.
#define P1_LD(k) (*(const float4*)(qptr + (size_t)(k) * NN))

#define P1_STEP(QV, sidx) { \
    float t16 = QV.x + QV.y + QV.z + QV.w; \
    float t0  = dot4(p0,  QV); float t1  = dot4(p1,  QV); \
    float t2  = dot4(p2,  QV); float t3  = dot4(p3,  QV); \
    float t4  = dot4(p4,  QV); float t5  = dot4(p5,  QV); \
    float t6  = dot4(p6,  QV); float t7  = dot4(p7,  QV); \
    float t8  = dot4(p8,  QV); float t9  = dot4(p9,  QV); \
    float t10 = dot4(p10, QV); float t11 = dot4(p11, QV); \
    float t12 = dot4(p12, QV); float t13 = dot4(p13, QV); \
    float t14 = dot4(p14, QV); float t15 = dot4(p15, QV); \
    t0  = dpp_sum64(t0);  t1  = dpp_sum64(t1);  t2  = dpp_sum64(t2); \
    t3  = dpp_sum64(t3);  t4  = dpp_sum64(t4);  t5  = dpp_sum64(t5); \
    t6  = dpp_sum64(t6);  t7  = dpp_sum64(t7);  t8  = dpp_sum64(t8); \
    t9  = dpp_sum64(t9);  t10 = dpp_sum64(t10); t11 = dpp_sum64(t11); \
    t12 = dpp_sum64(t12); t13 = dpp_sum64(t13); t14 = dpp_sum64(t14); \
    t15 = dpp_sum64(t15); t16 = dpp_sum64(t16); \
    if (lane == 63) { \
        float* o = sout + (size_t)(sidx) * 17; \
        o[0] = t0;  o[1] = t1;  o[2] = t2;  o[3] = t3; \
        o[4] = t4;  o[5] = t5;  o[6] = t6;  o[7] = t7; \
        o[8] = t8;  o[9] = t9;  o[10] = t10; o[11] = t11; \
        o[12] = t12; o[13] = t13; o[14] = t14; o[15] = t15; \
        o[16] = t16; \
    } }

__global__ __launch_bounds__(256) void k_pass1(const float* __restrict__ pf,
                                               const float* __restrict__ Q1,
                                               const float* __restrict__ Q2,
                                               float* __restrict__ ws) {
    int tid = threadIdx.x, wid = tid >> 6, lane = tid & 63;
    int W = blockIdx.x * 4 + wid;      // 0..2047
    int bq  = W >> 8;                  // 0..7
    int win = W & 255;                 // 0..255
    int b = bq >> 1, q = bq & 1;

    int nbase = win * 256 + lane * 4;  // this lane's 4-px slice
    const float* qptr = (q ? Q2 : Q1) + (size_t)b * SS * NN + nbase;
    const float* PF   = pf + (size_t)b * CC * NN + nbase;

    // pf: 16 channels x this lane's float4, persistent in registers
    float4 p0  = *(const float4*)(PF + (size_t)0  * NN);
    float4 p1  = *(const float4*)(PF + (size_t)1  * NN);
    float4 p2  = *(const float4*)(PF + (size_t)2  * NN);
    float4 p3  = *(const float4*)(PF + (size_t)3  * NN);
    float4 p4  = *(const float4*)(PF + (size_t)4  * NN);
    float4 p5  = *(const float4*)(PF + (size_t)5  * NN);
    float4 p6  = *(const float4*)(PF + (size_t)6  * NN);
    float4 p7  = *(const float4*)(PF + (size_t)7  * NN);
    float4 p8  = *(const float4*)(PF + (size_t)8  * NN);
    float4 p9  = *(const float4*)(PF + (size_t)9  * NN);
    float4 p10 = *(const float4*)(PF + (size_t)10 * NN);
    float4 p11 = *(const float4*)(PF + (size_t)11 * NN);
    float4 p12 = *(const float4*)(PF + (size_t)12 * NN);
    float4 p13 = *(const float4*)(PF + (size_t)13 * NN);
    float4 p14 = *(const float4*)(PF + (size_t)14 * NN);
    float4 p15 = *(const float4*)(PF + (size_t)15 * NN);

    float* sout = ws + PPART_OFF + (size_t)(bq * 256 + win) * 1700;

    float4 qA = P1_LD(0), qB = P1_LD(1), qC = P1_LD(2), qD = P1_LD(3);
    for (int s = 0; s < 96; s += 4) {
        P1_STEP(qA, s)     qA = P1_LD(s + 4);
        P1_STEP(qB, s + 1) qB = P1_LD(s + 5);
        P1_STEP(qC, s + 2) qC = P1_LD(s + 6);
        P1_STEP(qD, s + 3) qD = P1_LD(s + 7);
    }
    P1_STEP(qA, 96)
    P1_STEP(qB, 97)
    P1_STEP(qC, 98)
    P1_STEP(qD, 99)
}

// ---------------- K2: reduce window partials ----------------
// PQ[bq][wgrp][1700] = sum over 16 windows of PPART. Coalesced.
__global__ __launch_bounds__(256) void k_reduceP(float* __restrict__ ws) {
    int wg = blockIdx.x;   // 0..15
    int bq = blockIdx.y;   // 0..7
    int tid = threadIdx.x;
    const float* pp = ws + PPART_OFF + ((size_t)bq * 256 + wg * 16) * 1700;
    float a0 = 0.f, a1 = 0.f, a2 = 0.f, a3 = 0.f, a4 = 0.f, a5 = 0.f, a6 = 0.f;
    for (int wv = 0; wv < 16; ++wv) {
        const float* p = pp + (size_t)wv * 1700;
        a0 += p[tid];
        a1 += p[256 + tid];
        a2 += p[512 + tid];
        a3 += p[768 + tid];
        a4 += p[1024 + tid];
        a5 += p[1280 + tid];
        a6 += (1536 + tid < 1700) ? p[1536 + tid] : 0.f;
    }
    float* o = ws + PQ_OFF + ((size_t)bq * 16 + wg) * 1700;
    o[tid] = a0; o[256 + tid] = a1; o[512 + tid] = a2; o[768 + tid] = a3;
    o[1024 + tid] = a4; o[1280 + tid] = a5;
    if (1536 + tid < 1700) o[1536 + tid] = a6;
}

// ---------------- K3: rels + finalize ----------------
__global__ __launch_bounds__(256) void k_finalize(const float* __restrict__ spf1,
                                                  const float* __restrict__ spf2,
                                                  float* __restrict__ ws) {
    int bq = blockIdx.x;  // 0..7
    int b = bq >> 1, q = bq & 1;
    __shared__ float sp[CC][SS];
    __shared__ float rl[SS][SS + 1];
    __shared__ float Pl[CC * SS];
    __shared__ float qs[SS];
    __shared__ float den[SS];
    int tid = threadIdx.x;

    const float* spf = (q ? spf2 : spf1) + (size_t)b * CC * SS;
    for (int i = tid; i < CC * SS; i += 256) sp[i / SS][i % SS] = spf[i];
    __syncthreads();
    for (int i = tid; i < SS * SS; i += 256) {
        int s = i / SS, t = i % SS;
        float d2 = 0.f;
        #pragma unroll
        for (int c = 0; c < CC; ++c) {
            float d = sp[c][t] - sp[c][s];
            d2 += d * d;
        }
        rl[s][t] = expf(-d2);
    }
    // reduce the 16 window-group partials. PQ slot layout: [s][17c]
    const float* pq = ws + PQ_OFF + (size_t)bq * 16 * 1700;
    for (int idx = tid; idx < CC * SS; idx += 256) {
        int c = idx / SS, s = idx % SS;
        float v = 0.f;
        #pragma unroll 4
        for (int g = 0; g < 16; ++g) v += pq[(size_t)g * 1700 + s * 17 + c];
        Pl[idx] = v;
    }
    if (tid < SS) {
        float v = 0.f;
        #pragma unroll 4
        for (int g = 0; g < 16; ++g) v += pq[(size_t)g * 1700 + tid * 17 + 16];
        qs[tid] = v;
    }
    __syncthreads();
    if (tid < SS) {
        float a = 0.f;
        for (int t = 0; t < SS; ++t) a += rl[tid][t] * qs[t];
        den[tid] = a + EPSV;
    }
    __syncthreads();
    float* sout = ws + SPFN_OFF + (size_t)bq * CC * SS;
    for (int idx = tid; idx < CC * SS; idx += 256) {
        int c = idx / SS, s = idx % SS;
        float a = 0.f;
        for (int t = 0; t < SS; ++t) a += rl[s][t] * Pl[c * SS + t];
        sout[idx] = a / den[s];
    }
}

// ---------------- K4: pf_sp = spf1n@Q1 + spf2n@Q2 ----------------
#define P2FMA(X, s) { \
    _Pragma("unroll") for (int g = 0; g < 4; ++g) { \
        float4 s1 = *(const float4*)&sp[0][s][g * 4]; \
        float4 s2 = *(const float4*)&sp[1][s][g * 4]; \
        fma2g(acc[g*4+0], s1.x, X##1, s2.x, X##2); \
        fma2g(acc[g*4+1], s1.y, X##1, s2.y, X##2); \
        fma2g(acc[g*4+2], s1.z, X##1, s2.z, X##2); \
        fma2g(acc[g*4+3], s1.w, X##1, s2.w, X##2); } }

__global__ __launch_bounds__(128) void k_pass2(const float* __restrict__ Q1,
                                               const float* __restrict__ Q2,
                                               float* __restrict__ ws) {
    int blk = blockIdx.x;   // 0..255
    int b   = blockIdx.y;
    __shared__ float sp[2][SS][CC];
    int tid = threadIdx.x;
    const float* spin = ws + SPFN_OFF + (size_t)b * 2 * CC * SS;
    for (int idx = tid; idx < 2 * CC * SS; idx += 128) {
        int qq = idx / (CC * SS), rem = idx % (CC * SS);
        int c = rem / SS, s = rem % SS;
        sp[qq][s][c] = spin[idx];
    }
    __syncthreads();
    int n = blk * 256 + tid * 2;
    const float* q1p = Q1 + (size_t)b * SS * NN + n;
    const float* q2p = Q2 + (size_t)b * SS * NN + n;
    float2 acc[CC];
    #pragma unroll
    for (int c = 0; c < CC; ++c) acc[c] = make_float2(0.f, 0.f);
    float2 A1, A2, B1, B2;
    A1 = *(const float2*)(q1p);
    A2 = *(const float2*)(q2p);
    #pragma unroll 2
    for (int s = 0; s < 98; s += 2) {
        B1 = *(const float2*)(q1p + (size_t)(s + 1) * NN);
        B2 = *(const float2*)(q2p + (size_t)(s + 1) * NN);
        P2FMA(A, s)
        A1 = *(const float2*)(q1p + (size_t)(s + 2) * NN);
        A2 = *(const float2*)(q2p + (size_t)(s + 2) * NN);
        P2FMA(B, s + 1)
    }
    B1 = *(const float2*)(q1p + (size_t)99 * NN);
    B2 = *(const float2*)(q2p + (size_t)99 * NN);
    P2FMA(A, 98)
    P2FMA(B, 99)
    float* o = ws + PFSP_OFF + (size_t)b * CC * NN + n;
    #pragma unroll
    for (int c = 0; c < CC; ++c)
        *(float2*)(o + (size_t)c * NN) = acc[c];
}

// ---------------- K5: 3x3 conv, 16 -> 2 channels, + bias ----------------
__global__ __launch_bounds__(256) void k_conv(const float* __restrict__ w_ds,
                                              const float* __restrict__ b_ds,
                                              const float* __restrict__ ws,
                                              float* __restrict__ out) {
    int b = blockIdx.y;
    int n = blockIdx.x * 256 + threadIdx.x;
    __shared__ float wl[2][CC][9];
    __shared__ float bl[2];
    for (int i = threadIdx.x; i < 2 * CC * 9; i += 256)
        ((float*)wl)[i] = w_ds[i];
    if (threadIdx.x < 2) bl[threadIdx.x] = b_ds[threadIdx.x];
    __syncthreads();
    int y = n >> 8, x = n & 255;
    const float* base = ws + PFSP_OFF + (size_t)b * CC * NN;
    float a0 = bl[0], a1 = bl[1];
    for (int c = 0; c < CC; ++c) {
        const float* pc = base + (size_t)c * NN;
        #pragma unroll
        for (int dy = -1; dy <= 1; ++dy) {
            int yy = y + dy;
            if (yy < 0 || yy >= HH) continue;
            #pragma unroll
            for (int dx = -1; dx <= 1; ++dx) {
                int xx = x + dx;
                if (xx < 0 || xx >= WW) continue;
                float v = pc[(size_t)yy * WW + xx];
                int k = (dy + 1) * 3 + (dx + 1);
                a0 += v * wl[0][c][k];
                a1 += v * wl[1][c][k];
            }
        }
    }
    out[((size_t)b * 2 + 0) * NN + n] = a0;
    out[((size_t)b * 2 + 1) * NN + n] = a1;
}

extern "C" void kernel_launch(void* const* d_in, const int* in_sizes, int n_in,
                              void* d_out, int out_size, void* d_ws, size_t ws_size,
                              hipStream_t stream) {
    const float* pf   = (const float*)d_in[0];
    const float* spf1 = (const float*)d_in[1];
    const float* spf2 = (const float*)d_in[2];
    const float* Q1   = (const float*)d_in[3];
    const float* Q2   = (const float*)d_in[4];
    const float* w_ds = (const float*)d_in[5];
    const float* b_ds = (const float*)d_in[6];
    float* ws  = (float*)d_ws;
    float* out = (float*)d_out;

    k_pass1<<<512, 256, 0, stream>>>(pf, Q1, Q2, ws);
    k_reduceP<<<dim3(16, 8), 256, 0, stream>>>(ws);
    k_finalize<<<8, 256, 0, stream>>>(spf1, spf2, ws);
    k_pass2<<<dim3(NN / 256, BB), 128, 0, stream>>>(Q1, Q2, ws);
    k_conv<<<dim3(NN / 256, BB), 256, 0, stream>>>(w_ds, b_ds, ws, out);
}

// Round 10
// 160.043 us; speedup vs baseline: 5.1155x; 1.3047x over previous
//
#include <hip/hip_runtime.h>

// Problem constants
#define BB 4
#define CC 16
#define HH 256
#define WW 256
#define NN (HH*WW)      // 65536
#define SS 100
#define SPL 5           // s-split: 20 s per wave
#define EPSV 1e-32f

// ws layout (float offsets)
#define PQ_OFF    0u                      // [8 bq][8 wgrp][1700]            = 108800
#define SPFN_OFF  217600u                 // [8 bq][16 c][100 s]             = 12800
#define PFSP_OFF  230400u                 // [4][16][65536]                  = 4194304
#define PPART_OFF PFSP_OFF                // [8][64 win][2 nh][5 sp][20][17] = 1740800
// PPART aliases PFSP: consumed by k_reduceP/k_finalize before k_pass2 overwrites.

__device__ __forceinline__ float dot4(const float4& a, const float4& b) {
    return a.x * b.x + a.y * b.y + a.z * b.z + a.w * b.w;
}
__device__ __forceinline__ void fma2g(float2& a, float c1, const float2& v1,
                                      float c2, const float2& v2) {
    a.x += c1 * v1.x + c2 * v2.x;
    a.y += c1 * v1.y + c2 * v2.y;
}

// DPP lane-read: x[src per ctrl]. MUST be used in uniform control flow only.
#define DPPQP(x, ctrl) __int_as_float(__builtin_amdgcn_update_dpp( \
    0, __float_as_int(x), ctrl, 0xF, 0xF, true))
// ctrl: 0xB1 quad_perm xor1; 0x4E quad_perm xor2; 0x114 row_shr:4; 0x118 row_shr:8

// Full 64-lane sum (result in lane 63) - verified in R8.
__device__ __forceinline__ float dpp_sum64(float x) {
    #define DPPADD(ctrl) \
        x += __int_as_float(__builtin_amdgcn_update_dpp( \
            0, __float_as_int(x), ctrl, 0xF, 0xF, true));
    DPPADD(0x111)  // row_shr:1
    DPPADD(0x112)  // row_shr:2
    DPPADD(0x114)  // row_shr:4
    DPPADD(0x118)  // row_shr:8
    DPPADD(0x142)  // row_bcast:15
    DPPADD(0x143)  // row_bcast:31 -> lane63 = all 64
    #undef DPPADD
    return x;
}

// ---------------- pass1 (K1) ----------------
// Wave owns (bq, 512-px half-window, 8-channel half, 20-s slice).
// pf in 16 float4 regs (8c x 2 positions). Per s: TWO 1KB coalesced Q loads,
// 16 dot4, then merge-reduce with ALL cross-lane ops unconditional (R9 bug:
// DPP inside ternary operands -> divergent branch -> DPP reads disabled
// lanes -> zeros. Selects now operate on already-computed values only):
//   pair-add (DPP xor1) -> select odd -> quad-add (DPP xor2) -> select hi2
//   -> 2 regs striped channel=lane&3 -> row_shr4+8 -> shfl_xor 16,32.
// Lanes 12-15 store 8 channels; lane 63 stores qsum (h==0 waves).
#define P1_LD0(k) (*(const float4*)(qptr + (size_t)(k) * NN))
#define P1_LD1(k) (*(const float4*)(qptr + (size_t)(k) * NN + 256))

#define P1_STEP(Q0, Q1, sidx) { \
    float t0 = dot4(p00,Q0)+dot4(p01,Q1), t1 = dot4(p10,Q0)+dot4(p11,Q1); \
    float t2 = dot4(p20,Q0)+dot4(p21,Q1), t3 = dot4(p30,Q0)+dot4(p31,Q1); \
    float t4 = dot4(p40,Q0)+dot4(p41,Q1), t5 = dot4(p50,Q0)+dot4(p51,Q1); \
    float t6 = dot4(p60,Q0)+dot4(p61,Q1), t7 = dot4(p70,Q0)+dot4(p71,Q1); \
    t0 += DPPQP(t0,0xB1); t1 += DPPQP(t1,0xB1); \
    t2 += DPPQP(t2,0xB1); t3 += DPPQP(t3,0xB1); \
    t4 += DPPQP(t4,0xB1); t5 += DPPQP(t5,0xB1); \
    t6 += DPPQP(t6,0xB1); t7 += DPPQP(t7,0xB1); \
    float u0 = odd ? t1 : t0; float u1 = odd ? t3 : t2; \
    float u2 = odd ? t5 : t4; float u3 = odd ? t7 : t6; \
    u0 += DPPQP(u0,0x4E); u1 += DPPQP(u1,0x4E); \
    u2 += DPPQP(u2,0x4E); u3 += DPPQP(u3,0x4E); \
    float w0 = hi2 ? u1 : u0; float w1 = hi2 ? u3 : u2; \
    w0 += DPPQP(w0,0x114); w1 += DPPQP(w1,0x114); \
    w0 += DPPQP(w0,0x118); w1 += DPPQP(w1,0x118); \
    w0 += __shfl_xor(w0,16); w1 += __shfl_xor(w1,16); \
    w0 += __shfl_xor(w0,32); w1 += __shfl_xor(w1,32); \
    float qv = Q0.x+Q0.y+Q0.z+Q0.w + Q1.x+Q1.y+Q1.z+Q1.w; \
    qv = dpp_sum64(qv); \
    if (h == 0 && lane == 63) sout[(size_t)(sidx)*17 + 16] = qv; \
    if (lane >= 12 && lane < 16) { \
        float* o = sout + (size_t)(sidx)*17 + h*8 + (lane-12); \
        o[0] = w0; o[4] = w1; \
    } \
}

__global__ __launch_bounds__(256, 4) void k_pass1(const float* __restrict__ pf,
                                                  const float* __restrict__ Q1,
                                                  const float* __restrict__ Q2,
                                                  float* __restrict__ ws) {
    int tid = threadIdx.x, wid = tid >> 6, lane = tid & 63;
    int h  = wid & 1;          // channel half
    int nh = wid >> 1;         // n half
    int win = blockIdx.x;      // 0..63 (1024-px window)
    int sp  = blockIdx.y;      // 0..4
    int bq  = blockIdx.z;      // 0..7
    int b = bq >> 1, q = bq & 1;
    bool odd = lane & 1;
    bool hi2 = lane & 2;

    int nbase = win * 1024 + nh * 512 + lane * 4;
    const float* qptr = (q ? Q2 : Q1) + (size_t)b * SS * NN
                        + (size_t)(sp * 20) * NN + nbase;
    const float* PF   = pf + (size_t)b * CC * NN + (size_t)(h * 8) * NN + nbase;

    // pf: 8 channels x 2 positions, persistent in registers (64 VGPR)
    float4 p00 = *(const float4*)(PF + (size_t)0 * NN);
    float4 p01 = *(const float4*)(PF + (size_t)0 * NN + 256);
    float4 p10 = *(const float4*)(PF + (size_t)1 * NN);
    float4 p11 = *(const float4*)(PF + (size_t)1 * NN + 256);
    float4 p20 = *(const float4*)(PF + (size_t)2 * NN);
    float4 p21 = *(const float4*)(PF + (size_t)2 * NN + 256);
    float4 p30 = *(const float4*)(PF + (size_t)3 * NN);
    float4 p31 = *(const float4*)(PF + (size_t)3 * NN + 256);
    float4 p40 = *(const float4*)(PF + (size_t)4 * NN);
    float4 p41 = *(const float4*)(PF + (size_t)4 * NN + 256);
    float4 p50 = *(const float4*)(PF + (size_t)5 * NN);
    float4 p51 = *(const float4*)(PF + (size_t)5 * NN + 256);
    float4 p60 = *(const float4*)(PF + (size_t)6 * NN);
    float4 p61 = *(const float4*)(PF + (size_t)6 * NN + 256);
    float4 p70 = *(const float4*)(PF + (size_t)7 * NN);
    float4 p71 = *(const float4*)(PF + (size_t)7 * NN + 256);

    float* sout = ws + PPART_OFF
                + (size_t)((((bq * 64 + win) * 2 + nh) * SPL) + sp) * (20 * 17);

    float4 A0 = P1_LD0(0), A1 = P1_LD1(0), B0, B1;
    for (int s = 0; s < 17; s += 2) {
        B0 = P1_LD0(s + 1); B1 = P1_LD1(s + 1);
        P1_STEP(A0, A1, s)
        A0 = P1_LD0(s + 2); A1 = P1_LD1(s + 2);
        P1_STEP(B0, B1, s + 1)
    }
    B0 = P1_LD0(19); B1 = P1_LD1(19);
    P1_STEP(A0, A1, 18)
    P1_STEP(B0, B1, 19)
}

// ---------------- K2: reduce window partials ----------------
// 128 windows (win,nh) of 1700 floats per bq -> PQ[bq][8 wgrp][1700].
__global__ __launch_bounds__(256) void k_reduceP(float* __restrict__ ws) {
    int wg = blockIdx.x;   // 0..7
    int bq = blockIdx.y;   // 0..7
    int tid = threadIdx.x;
    const float* pp = ws + PPART_OFF + (size_t)(bq * 128 + wg * 16) * 1700;
    float a0 = 0.f, a1 = 0.f, a2 = 0.f, a3 = 0.f, a4 = 0.f, a5 = 0.f, a6 = 0.f;
    for (int wv = 0; wv < 16; ++wv) {
        const float* p = pp + (size_t)wv * 1700;
        a0 += p[tid];
        a1 += p[256 + tid];
        a2 += p[512 + tid];
        a3 += p[768 + tid];
        a4 += p[1024 + tid];
        a5 += p[1280 + tid];
        a6 += (1536 + tid < 1700) ? p[1536 + tid] : 0.f;
    }
    float* o = ws + PQ_OFF + (size_t)(bq * 8 + wg) * 1700;
    o[tid] = a0; o[256 + tid] = a1; o[512 + tid] = a2; o[768 + tid] = a3;
    o[1024 + tid] = a4; o[1280 + tid] = a5;
    if (1536 + tid < 1700) o[1536 + tid] = a6;
}

// ---------------- K3: rels + finalize ----------------
// PQ slot layout [sp][20 s][17]: slot(s,c) = (s/20)*340 + (s%20)*17 + c
__global__ __launch_bounds__(256) void k_finalize(const float* __restrict__ spf1,
                                                  const float* __restrict__ spf2,
                                                  float* __restrict__ ws) {
    int bq = blockIdx.x;  // 0..7
    int b = bq >> 1, q = bq & 1;
    __shared__ float sp[CC][SS];
    __shared__ float rl[SS][SS + 1];
    __shared__ float Pl[CC * SS];
    __shared__ float qs[SS];
    __shared__ float den[SS];
    int tid = threadIdx.x;

    const float* spf = (q ? spf2 : spf1) + (size_t)b * CC * SS;
    for (int i = tid; i < CC * SS; i += 256) sp[i / SS][i % SS] = spf[i];
    __syncthreads();
    for (int i = tid; i < SS * SS; i += 256) {
        int s = i / SS, t = i % SS;
        float d2 = 0.f;
        #pragma unroll
        for (int c = 0; c < CC; ++c) {
            float d = sp[c][t] - sp[c][s];
            d2 += d * d;
        }
        rl[s][t] = expf(-d2);
    }
    const float* pq = ws + PQ_OFF + (size_t)bq * 8 * 1700;
    for (int idx = tid; idx < CC * SS; idx += 256) {
        int c = idx / SS, s = idx % SS;
        int slot = (s / 20) * 340 + (s % 20) * 17 + c;
        float v = 0.f;
        #pragma unroll 4
        for (int g = 0; g < 8; ++g) v += pq[(size_t)g * 1700 + slot];
        Pl[idx] = v;
    }
    if (tid < SS) {
        int slot = (tid / 20) * 340 + (tid % 20) * 17 + 16;
        float v = 0.f;
        #pragma unroll 4
        for (int g = 0; g < 8; ++g) v += pq[(size_t)g * 1700 + slot];
        qs[tid] = v;
    }
    __syncthreads();
    if (tid < SS) {
        float a = 0.f;
        for (int t = 0; t < SS; ++t) a += rl[tid][t] * qs[t];
        den[tid] = a + EPSV;
    }
    __syncthreads();
    float* sout = ws + SPFN_OFF + (size_t)bq * CC * SS;
    for (int idx = tid; idx < CC * SS; idx += 256) {
        int c = idx / SS, s = idx % SS;
        float a = 0.f;
        for (int t = 0; t < SS; ++t) a += rl[s][t] * Pl[c * SS + t];
        sout[idx] = a / den[s];
    }
}

// ---------------- K4: pf_sp = spf1n@Q1 + spf2n@Q2 ---------------- (unchanged)
#define P2FMA(X, s) { \
    _Pragma("unroll") for (int g = 0; g < 4; ++g) { \
        float4 s1 = *(const float4*)&sp[0][s][g * 4]; \
        float4 s2 = *(const float4*)&sp[1][s][g * 4]; \
        fma2g(acc[g*4+0], s1.x, X##1, s2.x, X##2); \
        fma2g(acc[g*4+1], s1.y, X##1, s2.y, X##2); \
        fma2g(acc[g*4+2], s1.z, X##1, s2.z, X##2); \
        fma2g(acc[g*4+3], s1.w, X##1, s2.w, X##2); } }

__global__ __launch_bounds__(128) void k_pass2(const float* __restrict__ Q1,
                                               const float* __restrict__ Q2,
                                               float* __restrict__ ws) {
    int blk = blockIdx.x;   // 0..255
    int b   = blockIdx.y;
    __shared__ float sp[2][SS][CC];
    int tid = threadIdx.x;
    const float* spin = ws + SPFN_OFF + (size_t)b * 2 * CC * SS;
    for (int idx = tid; idx < 2 * CC * SS; idx += 128) {
        int qq = idx / (CC * SS), rem = idx % (CC * SS);
        int c = rem / SS, s = rem % SS;
        sp[qq][s][c] = spin[idx];
    }
    __syncthreads();
    int n = blk * 256 + tid * 2;
    const float* q1p = Q1 + (size_t)b * SS * NN + n;
    const float* q2p = Q2 + (size_t)b * SS * NN + n;
    float2 acc[CC];
    #pragma unroll
    for (int c = 0; c < CC; ++c) acc[c] = make_float2(0.f, 0.f);
    float2 A1, A2, B1, B2;
    A1 = *(const float2*)(q1p);
    A2 = *(const float2*)(q2p);
    #pragma unroll 2
    for (int s = 0; s < 98; s += 2) {
        B1 = *(const float2*)(q1p + (size_t)(s + 1) * NN);
        B2 = *(const float2*)(q2p + (size_t)(s + 1) * NN);
        P2FMA(A, s)
        A1 = *(const float2*)(q1p + (size_t)(s + 2) * NN);
        A2 = *(const float2*)(q2p + (size_t)(s + 2) * NN);
        P2FMA(B, s + 1)
    }
    B1 = *(const float2*)(q1p + (size_t)99 * NN);
    B2 = *(const float2*)(q2p + (size_t)99 * NN);
    P2FMA(A, 98)
    P2FMA(B, 99)
    float* o = ws + PFSP_OFF + (size_t)b * CC * NN + n;
    #pragma unroll
    for (int c = 0; c < CC; ++c)
        *(float2*)(o + (size_t)c * NN) = acc[c];
}

// ---------------- K5: 3x3 conv, 16 -> 2 channels, + bias ---------------- (unchanged)
__global__ __launch_bounds__(256) void k_conv(const float* __restrict__ w_ds,
                                              const float* __restrict__ b_ds,
                                              const float* __restrict__ ws,
                                              float* __restrict__ out) {
    int b = blockIdx.y;
    int n = blockIdx.x * 256 + threadIdx.x;
    __shared__ float wl[2][CC][9];
    __shared__ float bl[2];
    for (int i = threadIdx.x; i < 2 * CC * 9; i += 256)
        ((float*)wl)[i] = w_ds[i];
    if (threadIdx.x < 2) bl[threadIdx.x] = b_ds[threadIdx.x];
    __syncthreads();
    int y = n >> 8, x = n & 255;
    const float* base = ws + PFSP_OFF + (size_t)b * CC * NN;
    float a0 = bl[0], a1 = bl[1];
    for (int c = 0; c < CC; ++c) {
        const float* pc = base + (size_t)c * NN;
        #pragma unroll
        for (int dy = -1; dy <= 1; ++dy) {
            int yy = y + dy;
            if (yy < 0 || yy >= HH) continue;
            #pragma unroll
            for (int dx = -1; dx <= 1; ++dx) {
                int xx = x + dx;
                if (xx < 0 || xx >= WW) continue;
                float v = pc[(size_t)yy * WW + xx];
                int k = (dy + 1) * 3 + (dx + 1);
                a0 += v * wl[0][c][k];
                a1 += v * wl[1][c][k];
            }
        }
    }
    out[((size_t)b * 2 + 0) * NN + n] = a0;
    out[((size_t)b * 2 + 1) * NN + n] = a1;
}

extern "C" void kernel_launch(void* const* d_in, const int* in_sizes, int n_in,
                              void* d_out, int out_size, void* d_ws, size_t ws_size,
                              hipStream_t stream) {
    const float* pf   = (const float*)d_in[0];
    const float* spf1 = (const float*)d_in[1];
    const float* spf2 = (const float*)d_in[2];
    const float* Q1   = (const float*)d_in[3];
    const float* Q2   = (const float*)d_in[4];
    const float* w_ds = (const float*)d_in[5];
    const float* b_ds = (const float*)d_in[6];
    float* ws  = (float*)d_ws;
    float* out = (float*)d_out;

    k_pass1<<<dim3(64, SPL, 8), 256, 0, stream>>>(pf, Q1, Q2, ws);
    k_reduceP<<<dim3(8, 8), 256, 0, stream>>>(ws);
    k_finalize<<<8, 256, 0, stream>>>(spf1, spf2, ws);
    k_pass2<<<dim3(NN / 256, BB), 128, 0, stream>>>(Q1, Q2, ws);
    k_conv<<<dim3(NN / 256, BB), 256, 0, stream>>>(w_ds, b_ds, ws, out);
}